// Round 1
// 524.521 us; speedup vs baseline: 1.0156x; 1.0156x over previous
//
#include <hip/hip_runtime.h>

typedef unsigned short ushort_t;
typedef unsigned int uint_t;
typedef __attribute__((ext_vector_type(8))) short s8v;     // 8 x bf16 (4 VGPRs)
typedef __attribute__((ext_vector_type(4))) float f4v;     // 4 x fp32 (native vec, NT-load ok)

// Problem constants (fixed by the reference)
#define NS0 100000
#define ND0 20000
#define ND1 4000
#define E0  640000
#define E1  128000
#define F   512     // IN_F == HID_F
#define OF  256
#define NCNT (NS0 + ND0 + ND0 + ND1)   // 144000
#define SB  96                          // bucket stride; Poisson(32) max deg ~57, P(>96)~1e-16

#define WBLK ((F * F + F * OF) / 256)      // 1536
#define XBLK (NS0 * 128 / 256)             // 50000

__device__ __forceinline__ ushort_t f2b(float f) {
    uint_t u = __float_as_uint(f);
    uint_t r = (u + 0x7fffu + ((u >> 16) & 1u)) >> 16;
    return (ushort_t)r;
}
__device__ __forceinline__ float b2f_lo(uint_t u) { return __uint_as_float(u << 16); }
__device__ __forceinline__ float b2f_hi(uint_t u) { return __uint_as_float(u & 0xffff0000u); }

// FUSED front kernel: bucket-fill (blocks [0,750)) runs CONCURRENTLY with the
// W transpose-convert (blocks [750,750+WBLK)) and the x fp32->bf16 stream
// (remaining blocks). bucket_fill is atomic-latency-bound, conv is HBM-BW-bound
// -> complementary pipes; previously they were serialized on the stream.
// Bucket blocks are FIRST so they launch in dispatch round 0 and finish under
// the ~50us conv stream (put last they would serialize again).
// x reads NON-TEMPORAL: the 205 MB stream must not evict xb from L3 (the L1
// gather re-reads xb ~6.4x and needs it L3-resident; R1: 313MB fetch vs 102MB ws).
__global__ __launch_bounds__(256) void prep(const int* __restrict__ src0, const int* __restrict__ dst0,
                                            const int* __restrict__ src1, const int* __restrict__ dst1,
                                            int* __restrict__ cntOut0, int* __restrict__ cntIn0,
                                            int* __restrict__ cntOut1, int* __restrict__ cntIn1,
                                            int* __restrict__ es0, int* __restrict__ es1,
                                            const float* __restrict__ W1, const float* __restrict__ W2,
                                            ushort_t* __restrict__ wt1, ushort_t* __restrict__ wt2,
                                            const float* __restrict__ x, ushort_t* __restrict__ xb) {
    int b = blockIdx.x;
    if (b < 625) {
        // layer-0 edges: E0 = 640000 = 625*1024; 4 edges/thread via int4 for atomic MLP
        int e = (b * 256 + threadIdx.x) * 4;
        int4 s = *(const int4*)(src0 + e);
        int4 d = *(const int4*)(dst0 + e);
        atomicAdd(&cntOut0[s.x], 1);
        atomicAdd(&cntOut0[s.y], 1);
        atomicAdd(&cntOut0[s.z], 1);
        atomicAdd(&cntOut0[s.w], 1);
        int p0 = atomicAdd(&cntIn0[d.x], 1);
        int p1 = atomicAdd(&cntIn0[d.y], 1);
        int p2 = atomicAdd(&cntIn0[d.z], 1);
        int p3 = atomicAdd(&cntIn0[d.w], 1);
        es0[d.x * SB + min(p0, SB - 1)] = s.x;
        es0[d.y * SB + min(p1, SB - 1)] = s.y;
        es0[d.z * SB + min(p2, SB - 1)] = s.z;
        es0[d.w * SB + min(p3, SB - 1)] = s.w;
        return;
    }
    if (b < 750) {
        // layer-1 edges: E1 = 128000 = 125*1024
        int e = ((b - 625) * 256 + threadIdx.x) * 4;
        int4 s = *(const int4*)(src1 + e);
        int4 d = *(const int4*)(dst1 + e);
        atomicAdd(&cntOut1[s.x], 1);
        atomicAdd(&cntOut1[s.y], 1);
        atomicAdd(&cntOut1[s.z], 1);
        atomicAdd(&cntOut1[s.w], 1);
        int p0 = atomicAdd(&cntIn1[d.x], 1);
        int p1 = atomicAdd(&cntIn1[d.y], 1);
        int p2 = atomicAdd(&cntIn1[d.z], 1);
        int p3 = atomicAdd(&cntIn1[d.w], 1);
        es1[d.x * SB + min(p0, SB - 1)] = s.x;
        es1[d.y * SB + min(p1, SB - 1)] = s.y;
        es1[d.z * SB + min(p2, SB - 1)] = s.z;
        es1[d.w * SB + min(p3, SB - 1)] = s.w;
        return;
    }
    int bb = b - 750;
    if (bb < WBLK) {
        int i = bb * 256 + threadIdx.x;
        if (i < F * F) {
            int k = i >> 9, n = i & (F - 1);
            wt1[n * F + k] = f2b(W1[i]);
        } else {
            int j = i - F * F;
            int k = j >> 8, n = j & (OF - 1);
            wt2[n * F + k] = f2b(W2[j]);
        }
        return;
    }
    int i = (bb - WBLK) * 256 + threadIdx.x;   // quad index; 128 quads per row; XBLK*256 == NS0*128 exactly
    f4v v = __builtin_nontemporal_load(((const f4v*)x) + i);
    uint2 o;
    o.x = (uint_t)f2b(v.x) | ((uint_t)f2b(v.y) << 16);
    o.y = (uint_t)f2b(v.z) | ((uint_t)f2b(v.w) << 16);
    ((uint2*)xb)[i] = o;
}

__device__ __forceinline__ void fma8(float* acc, uint4 u, float sc) {
    acc[0] += b2f_lo(u.x) * sc; acc[1] += b2f_hi(u.x) * sc;
    acc[2] += b2f_lo(u.y) * sc; acc[3] += b2f_hi(u.y) * sc;
    acc[4] += b2f_lo(u.z) * sc; acc[5] += b2f_hi(u.z) * sc;
    acc[6] += b2f_lo(u.w) * sc; acc[7] += b2f_hi(u.w) * sc;
}
__device__ __forceinline__ void add8(float* acc, uint4 u) {
    acc[0] += b2f_lo(u.x); acc[1] += b2f_hi(u.x);
    acc[2] += b2f_lo(u.y); acc[3] += b2f_hi(u.y);
    acc[4] += b2f_lo(u.z); acc[5] += b2f_hi(u.z);
    acc[6] += b2f_lo(u.w); acc[7] += b2f_hi(u.w);
}

// L1 aggregation: one wave per dst row; 64 lanes x 16B = full 1024B row/load.
// Per-edge out-degree scale rsqrtf(cntOut[s]) applied during accumulate.
// Software-pipelined: next 8 edge ids are loaded WHILE the current 8 row
// gathers are in flight, breaking the per-iteration sload->gather->fma chain.
__global__ __launch_bounds__(256) void agg_l1(const ushort_t* __restrict__ X, const int* __restrict__ es,
                                              const int* __restrict__ cntIn, const int* __restrict__ cntOut,
                                              ushort_t* __restrict__ out, int ndst) {
    int d = __builtin_amdgcn_readfirstlane(blockIdx.x * 4 + (threadIdx.x >> 6));
    if (d >= ndst) return;
    int lane = threadIdx.x & 63;
    int n = min(cntIn[d], SB);
    const int* ed = es + (size_t)d * SB;
    const uint4* Xv = (const uint4*)X;
    float acc[8] = {0.f, 0.f, 0.f, 0.f, 0.f, 0.f, 0.f, 0.f};
    int i = 0;
    int nb = n & ~7;
    if (nb) {
        int sv[8];
        #pragma unroll
        for (int j = 0; j < 8; ++j) sv[j] = ed[j];
        while (true) {
            uint4 u[8];
            #pragma unroll
            for (int j = 0; j < 8; ++j) u[j] = Xv[(size_t)sv[j] * 64 + lane];
            float scv[8];
            #pragma unroll
            for (int j = 0; j < 8; ++j) scv[j] = rsqrtf(fmaxf((float)cntOut[sv[j]], 1.0f));
            i += 8;
            if (i < nb) {
                int sn[8];
                #pragma unroll
                for (int j = 0; j < 8; ++j) sn[j] = ed[i + j];   // prefetch while gathers in flight
                #pragma unroll
                for (int j = 0; j < 8; ++j) fma8(acc, u[j], scv[j]);
                #pragma unroll
                for (int j = 0; j < 8; ++j) sv[j] = sn[j];
            } else {
                #pragma unroll
                for (int j = 0; j < 8; ++j) fma8(acc, u[j], scv[j]);
                break;
            }
        }
    }
    for (; i < n; ++i) {
        int s = ed[i];
        float sc = rsqrtf(fmaxf((float)cntOut[s], 1.0f));
        fma8(acc, Xv[(size_t)s * 64 + lane], sc);
    }
    float sc = rsqrtf(fmaxf((float)n, 1.0f));
    uint4 o;
    o.x = (uint_t)f2b(acc[0] * sc) | ((uint_t)f2b(acc[1] * sc) << 16);
    o.y = (uint_t)f2b(acc[2] * sc) | ((uint_t)f2b(acc[3] * sc) << 16);
    o.z = (uint_t)f2b(acc[4] * sc) | ((uint_t)f2b(acc[5] * sc) << 16);
    o.w = (uint_t)f2b(acc[6] * sc) | ((uint_t)f2b(acc[7] * sc) << 16);
    ((uint4*)out)[(size_t)d * 64 + lane] = o;
}

// L2 aggregation: h is already out-degree-pre-scaled by gemm1's epilogue, so
// plain sum then in-degree scale. Unroll x16.
__global__ __launch_bounds__(256) void agg_l2(const ushort_t* __restrict__ X, const int* __restrict__ es,
                                              const int* __restrict__ cntIn, ushort_t* __restrict__ out,
                                              int ndst) {
    int d = __builtin_amdgcn_readfirstlane(blockIdx.x * 4 + (threadIdx.x >> 6));
    if (d >= ndst) return;
    int lane = threadIdx.x & 63;
    int n = min(cntIn[d], SB);
    const int* ed = es + (size_t)d * SB;
    const uint4* Xv = (const uint4*)X;
    float acc[8] = {0.f, 0.f, 0.f, 0.f, 0.f, 0.f, 0.f, 0.f};
    int i = 0;
    for (; i + 16 <= n; i += 16) {
        uint4 u[16];
        #pragma unroll
        for (int j = 0; j < 16; ++j) u[j] = Xv[(size_t)ed[i + j] * 64 + lane];
        #pragma unroll
        for (int j = 0; j < 16; ++j) add8(acc, u[j]);
    }
    for (; i + 4 <= n; i += 4) {
        uint4 u[4];
        #pragma unroll
        for (int j = 0; j < 4; ++j) u[j] = Xv[(size_t)ed[i + j] * 64 + lane];
        #pragma unroll
        for (int j = 0; j < 4; ++j) add8(acc, u[j]);
    }
    for (; i < n; ++i) add8(acc, Xv[(size_t)ed[i] * 64 + lane]);
    float sc = rsqrtf(fmaxf((float)n, 1.0f));
    uint4 o;
    o.x = (uint_t)f2b(acc[0] * sc) | ((uint_t)f2b(acc[1] * sc) << 16);
    o.y = (uint_t)f2b(acc[2] * sc) | ((uint_t)f2b(acc[3] * sc) << 16);
    o.z = (uint_t)f2b(acc[4] * sc) | ((uint_t)f2b(acc[5] * sc) << 16);
    o.w = (uint_t)f2b(acc[6] * sc) | ((uint_t)f2b(acc[7] * sc) << 16);
    ((uint4*)out)[(size_t)d * 64 + lane] = o;
}

// m97-style GEMM: C[M,N] = relu(A[M,K]bf16 @ BT[N,K]bf16^T + bias) (* rsqrt(rowCnt))
// 128x128 tile / 256 threads / BK=64; global_load_lds 16B staging; 32 MFMA per K-step/wave.
template <typename OutT>
__global__ __launch_bounds__(256) void gemm128(const ushort_t* __restrict__ A, const ushort_t* __restrict__ BT,
                                               const float* __restrict__ bias, const int* __restrict__ rowCnt,
                                               OutT* __restrict__ C, int M, int N, int K) {
    __shared__ __align__(16) ushort_t As[128 * 64];
    __shared__ __align__(16) ushort_t Bs[128 * 64];
    int tid = threadIdx.x;
    int lane = tid & 63, w = tid >> 6;
    int m16 = lane & 15, quad = lane >> 4;
    int wm = w & 1, wn = w >> 1;
    int bm = blockIdx.x * 128, bn = blockIdx.y * 128;
    f4v acc[4][4] = {};
    for (int k0 = 0; k0 < K; k0 += 64) {
        #pragma unroll
        for (int i = 0; i < 4; ++i) {
            int c = i * 256 + tid;          // chunk id: row = c>>3, 16B seg = c&7
            int row = c >> 3, seg = (c & 7) * 8;
            int ra = bm + row; if (ra >= M) ra = M - 1;
            __builtin_amdgcn_global_load_lds(
                (const __attribute__((address_space(1))) uint_t*)(A + (size_t)ra * K + k0 + seg),
                (__attribute__((address_space(3))) uint_t*)(As + (size_t)c * 8), 16, 0, 0);
        }
        #pragma unroll
        for (int i = 0; i < 4; ++i) {
            int c = i * 256 + tid;
            int row = c >> 3, seg = (c & 7) * 8;
            int rb = bn + row;              // N is a multiple of 128 here
            __builtin_amdgcn_global_load_lds(
                (const __attribute__((address_space(1))) uint_t*)(BT + (size_t)rb * K + k0 + seg),
                (__attribute__((address_space(3))) uint_t*)(Bs + (size_t)c * 8), 16, 0, 0);
        }
        __syncthreads();
        #pragma unroll
        for (int kc = 0; kc < 2; ++kc) {
            int co = kc * 32 + quad * 8;
            s8v af[4], bf[4];
            #pragma unroll
            for (int m = 0; m < 4; ++m)
                af[m] = *(const s8v*)&As[(wm * 64 + m * 16 + m16) * 64 + co];
            #pragma unroll
            for (int nn = 0; nn < 4; ++nn)
                bf[nn] = *(const s8v*)&Bs[(wn * 64 + nn * 16 + m16) * 64 + co];
            #pragma unroll
            for (int m = 0; m < 4; ++m)
                #pragma unroll
                for (int nn = 0; nn < 4; ++nn)
                    acc[m][nn] = __builtin_amdgcn_mfma_f32_16x16x32_bf16(af[m], bf[nn], acc[m][nn], 0, 0, 0);
        }
        __syncthreads();
    }
    #pragma unroll
    for (int m = 0; m < 4; ++m) {
        #pragma unroll
        for (int rr = 0; rr < 4; ++rr) {
            int row = bm + wm * 64 + m * 16 + quad * 4 + rr;
            if (row < M) {
                float rs = rowCnt ? rsqrtf(fmaxf((float)rowCnt[row], 1.0f)) : 1.0f;
                #pragma unroll
                for (int nn = 0; nn < 4; ++nn) {
                    int col = bn + wn * 64 + nn * 16 + m16;
                    float v = fmaxf(acc[m][nn][rr] + bias[col], 0.0f) * rs;
                    if (sizeof(OutT) == 2)
                        ((ushort_t*)C)[(size_t)row * N + col] = f2b(v);
                    else
                        ((float*)C)[(size_t)row * N + col] = v;
                }
            }
        }
    }
}

extern "C" void kernel_launch(void* const* d_in, const int* in_sizes, int n_in,
                              void* d_out, int out_size, void* d_ws, size_t ws_size,
                              hipStream_t stream) {
    (void)in_sizes; (void)n_in; (void)out_size; (void)ws_size;
    const float* x    = (const float*)d_in[0];
    const int*   src0 = (const int*)d_in[1];
    const int*   dst0 = (const int*)d_in[2];
    const int*   src1 = (const int*)d_in[3];
    const int*   dst1 = (const int*)d_in[4];
    const float* W1   = (const float*)d_in[5];
    const float* b1   = (const float*)d_in[6];
    const float* W2   = (const float*)d_in[7];
    const float* b2   = (const float*)d_in[8];
    float* out = (float*)d_out;

    char* p = (char*)d_ws;
    auto alloc = [&](size_t bytes) { char* q = p; p += (bytes + 255) & ~(size_t)255; return q; };
    int*      cnt  = (int*)alloc((size_t)NCNT * 4);
    int*      es0  = (int*)alloc((size_t)ND0 * SB * 4);
    int*      es1  = (int*)alloc((size_t)ND1 * SB * 4);
    ushort_t* wt1  = (ushort_t*)alloc((size_t)F * F * 2);
    ushort_t* wt2  = (ushort_t*)alloc((size_t)OF * F * 2);
    ushort_t* agg0 = (ushort_t*)alloc((size_t)ND0 * F * 2);
    ushort_t* h    = (ushort_t*)alloc((size_t)ND0 * F * 2);
    ushort_t* agg1 = (ushort_t*)alloc((size_t)ND1 * F * 2);
    ushort_t* xb   = (ushort_t*)alloc((size_t)NS0 * F * 2);

    int* cntOut0 = cnt;                      // [NS0]
    int* cntIn0  = cnt + NS0;                // [ND0]
    int* cntOut1 = cnt + NS0 + ND0;          // [ND0]
    int* cntIn1  = cnt + NS0 + ND0 + ND0;    // [ND1]

    (void)hipMemsetAsync(cnt, 0, (size_t)NCNT * 4, stream);

    prep<<<750 + WBLK + XBLK, 256, 0, stream>>>(src0, dst0, src1, dst1,
                                                cntOut0, cntIn0, cntOut1, cntIn1, es0, es1,
                                                W1, W2, wt1, wt2, x, xb);

    agg_l1<<<(ND0 + 3) / 4, 256, 0, stream>>>(xb, es0, cntIn0, cntOut0, agg0, ND0);

    gemm128<ushort_t><<<dim3((ND0 + 127) / 128, F / 128), 256, 0, stream>>>(
        agg0, wt1, b1, cntOut1, h, ND0, F, F);

    agg_l2<<<(ND1 + 3) / 4, 256, 0, stream>>>(h, es1, cntIn1, agg1, ND1);

    gemm128<float><<<dim3((ND1 + 127) / 128, OF / 128), 256, 0, stream>>>(
        agg1, wt2, b2, nullptr, out, ND1, OF, F);
}